// Round 1
// baseline (322.692 us; speedup 1.0000x reference)
//
#include <hip/hip_runtime.h>
#include <hip/hip_bf16.h>

// Problem: B=8, N=1024, F_IN=F_OUT=128, H=8, D_K=16.
// Pipeline: Q/K/V proj (GEMM) -> masked multi-head attention -> out proj (GEMM).
// All fp32 this round.

#define BATCH 8
#define NNODE 1024
#define FEAT  128
#define NHEAD 8
#define DKDIM 16

// ---------------------------------------------------------------------------
// GEMM: out[r][c] = sum_k X[r][k] * W[c][k] + bias[c]
// X: [R,128] row-major, W: [C,128] row-major (nn.Linear weight), out: [R,C].
// Block computes a 64x64 tile; 256 threads, each 4x4 outputs via float4 LDS reads.
// grid.x = R/64, grid.y = C/64.
// ---------------------------------------------------------------------------
__global__ __launch_bounds__(256) void gemm_xwt_kernel(
    const float* __restrict__ X, const float* __restrict__ W,
    const float* __restrict__ bias, float* __restrict__ out, int C) {
  // stride 68: 68%32==4 banks spread; 68*4B multiple of 16 -> float4 aligned
  __shared__ float Xs[128][68];
  __shared__ float Ws[128][68];
  const int t = threadIdx.x;
  const int r0blk = blockIdx.x * 64;
  const int c0blk = blockIdx.y * 64;

  // Stage tiles (coalesced global reads: consecutive lanes read consecutive k)
  #pragma unroll
  for (int it = 0; it < 32; ++it) {
    int idx = t + it * 256;       // 0..8191
    int k = idx & 127;
    int r = idx >> 7;             // 0..63
    Xs[k][r] = X[(size_t)(r0blk + r) * 128 + k];
    Ws[k][r] = W[(size_t)(c0blk + r) * 128 + k];
  }
  __syncthreads();

  const int rr = 4 * (t & 15);    // 0..60
  const int cc = 4 * (t >> 4);    // 0..60
  float acc[4][4] = {};

  #pragma unroll 8
  for (int k = 0; k < 128; ++k) {
    const float4 xv = *(const float4*)&Xs[k][rr];
    const float4 wv = *(const float4*)&Ws[k][cc];
    const float xa[4] = {xv.x, xv.y, xv.z, xv.w};
    const float wa[4] = {wv.x, wv.y, wv.z, wv.w};
    #pragma unroll
    for (int i = 0; i < 4; ++i)
      #pragma unroll
      for (int j = 0; j < 4; ++j)
        acc[i][j] += xa[i] * wa[j];
  }

  #pragma unroll
  for (int j = 0; j < 4; ++j) {
    const float bj = bias[c0blk + cc + j];
    #pragma unroll
    for (int i = 0; i < 4; ++i)
      out[(size_t)(r0blk + rr + i) * C + (c0blk + cc + j)] = acc[i][j] + bj;
  }
}

// ---------------------------------------------------------------------------
// Masked multi-head attention. One block (256 thr) per (b, query-row i).
// All 8 heads handled together: A-row scanned once, active-j list compacted,
// scores/softmax in LDS, PV gathered only over active columns.
// Q,K,V layout: [B*N, 128] with feature f = h*16 + d.
// ---------------------------------------------------------------------------
__global__ __launch_bounds__(256) void attn_kernel(
    const float* __restrict__ Qb, const float* __restrict__ Kb,
    const float* __restrict__ Vb, const float* __restrict__ A,
    float* __restrict__ Y) {
  __shared__ float sQ[128];
  __shared__ float sS[NHEAD][1032];     // stride 1032: 8h+j -> conflict-free reads
  __shared__ unsigned short sIdx[NNODE];
  __shared__ int sCount;
  __shared__ float sRedA[NHEAD][4];
  __shared__ float sMax[NHEAD];
  __shared__ float sInvSum[NHEAD];
  __shared__ float sOut[128];

  const int b = blockIdx.x >> 10;
  const int i = blockIdx.x & 1023;
  const int t = threadIdx.x;
  const int lane = t & 63;
  const int wv = t >> 6;

  if (t == 0) sCount = 0;
  if (t < 128) sQ[t] = Qb[((size_t)(b * NNODE + i)) * 128 + t] * 0.25f; // 1/sqrt(16)
  __syncthreads();

  // Phase 1: scan adjacency row, build compact active list
  const float* Arow = A + ((size_t)(b * NNODE + i)) * NNODE;
  #pragma unroll
  for (int jj = 0; jj < 4; ++jj) {
    int j = t + jj * 256;
    if (Arow[j] > 0.0f) {
      int slot = atomicAdd(&sCount, 1);
      sIdx[slot] = (unsigned short)j;
    }
  }
  __syncthreads();
  const int cnt = sCount;

  // Phase 2: scores for active columns (8 heads per K-row read)
  for (int idx = t; idx < cnt; idx += 256) {
    const int j = sIdx[idx];
    const float4* Kr = (const float4*)(Kb + ((size_t)(b * NNODE + j)) * 128);
    const float4* Qr = (const float4*)sQ;
    float s[NHEAD] = {};
    #pragma unroll
    for (int q = 0; q < 32; ++q) {
      const float4 kv = Kr[q];
      const float4 qv = Qr[q];
      s[q >> 2] += qv.x * kv.x + qv.y * kv.y + qv.z * kv.z + qv.w * kv.w;
    }
    #pragma unroll
    for (int h = 0; h < NHEAD; ++h) sS[h][j] = s[h];
  }
  __syncthreads();

  // Phase 3a: per-head max over active columns
  float lmax[NHEAD];
  #pragma unroll
  for (int h = 0; h < NHEAD; ++h) lmax[h] = -3.0e38f;
  for (int idx = t; idx < cnt; idx += 256) {
    const int j = sIdx[idx];
    #pragma unroll
    for (int h = 0; h < NHEAD; ++h) lmax[h] = fmaxf(lmax[h], sS[h][j]);
  }
  #pragma unroll
  for (int off = 32; off >= 1; off >>= 1)
    #pragma unroll
    for (int h = 0; h < NHEAD; ++h)
      lmax[h] = fmaxf(lmax[h], __shfl_xor(lmax[h], off));
  if (lane == 0)
    #pragma unroll
    for (int h = 0; h < NHEAD; ++h) sRedA[h][wv] = lmax[h];
  __syncthreads();
  if (t < NHEAD)
    sMax[t] = fmaxf(fmaxf(sRedA[t][0], sRedA[t][1]),
                    fmaxf(sRedA[t][2], sRedA[t][3]));
  __syncthreads();

  // Phase 3b: exponentiate in place, accumulate per-head sum
  float lsum[NHEAD] = {};
  for (int idx = t; idx < cnt; idx += 256) {
    const int j = sIdx[idx];
    #pragma unroll
    for (int h = 0; h < NHEAD; ++h) {
      const float p = __expf(sS[h][j] - sMax[h]);
      sS[h][j] = p;
      lsum[h] += p;
    }
  }
  #pragma unroll
  for (int off = 32; off >= 1; off >>= 1)
    #pragma unroll
    for (int h = 0; h < NHEAD; ++h) lsum[h] += __shfl_xor(lsum[h], off);
  if (lane == 0)
    #pragma unroll
    for (int h = 0; h < NHEAD; ++h) sRedA[h][wv] = lsum[h];
  __syncthreads();
  if (t < NHEAD)
    sInvSum[t] = 1.0f / (sRedA[t][0] + sRedA[t][1] + sRedA[t][2] + sRedA[t][3]);
  __syncthreads();

  // Phase 4: out[f] = sum_{active j} p[h][j] * V[j][f], f = h*16+d
  const int hd = t & 127;
  const int half = t >> 7;
  const int h = hd >> 4;
  float acc = 0.0f;
  for (int idx = half; idx < cnt; idx += 2) {
    const int j = sIdx[idx];
    acc += sS[h][j] * Vb[((size_t)(b * NNODE + j)) * 128 + hd];
  }
  if (half) sOut[hd] = acc;
  __syncthreads();
  if (t < 128) {
    const float y = (acc + sOut[t]) * sInvSum[h];
    Y[((size_t)(b * NNODE + i)) * 128 + t] = y;
  }
}

// ---------------------------------------------------------------------------
extern "C" void kernel_launch(void* const* d_in, const int* in_sizes, int n_in,
                              void* d_out, int out_size, void* d_ws, size_t ws_size,
                              hipStream_t stream) {
  const float* X  = (const float*)d_in[0];
  const float* A  = (const float*)d_in[1];
  const float* Wq = (const float*)d_in[2];
  const float* bq = (const float*)d_in[3];
  const float* Wk = (const float*)d_in[4];
  const float* bk = (const float*)d_in[5];
  const float* Wv = (const float*)d_in[6];
  const float* bv = (const float*)d_in[7];
  const float* Wo = (const float*)d_in[8];
  const float* bo = (const float*)d_in[9];
  float* out = (float*)d_out;

  const size_t mat = (size_t)BATCH * NNODE * FEAT;  // 1M floats = 4 MB
  float* Q = (float*)d_ws;
  float* K = Q + mat;
  float* V = K + mat;
  float* Yb = V + mat;

  dim3 gblk(128, 2);  // 8192/64 rows, 128/64 cols
  dim3 tblk(256);
  hipLaunchKernelGGL(gemm_xwt_kernel, gblk, tblk, 0, stream, X, Wq, bq, Q, FEAT);
  hipLaunchKernelGGL(gemm_xwt_kernel, gblk, tblk, 0, stream, X, Wk, bk, K, FEAT);
  hipLaunchKernelGGL(gemm_xwt_kernel, gblk, tblk, 0, stream, X, Wv, bv, V, FEAT);
  hipLaunchKernelGGL(attn_kernel, dim3(BATCH * NNODE), tblk, 0, stream, Q, K, V, A, Yb);
  hipLaunchKernelGGL(gemm_xwt_kernel, gblk, tblk, 0, stream, Yb, Wo, bo, out, FEAT);
}

// Round 2
// 233.283 us; speedup vs baseline: 1.3833x; 1.3833x over previous
//
#include <hip/hip_runtime.h>
#include <hip/hip_bf16.h>

// B=8, N=1024, F=128, H=8, d_k=16.
// QKV proj (GEMM) -> sparse masked multi-head attention -> out proj (GEMM).
// fp32 throughout.

#define BATCH 8
#define NNODE 1024
#define FEAT  128
#define NHEAD 8
#define CHUNK 512   // active-column chunk (avg cnt ~103, max ~140; online softmax handles overflow)

// ---------------------------------------------------------------------------
// GEMM: out[r][c] = sum_k X[r][k] * W[c][k] + bias[c]
// 1024 threads, 64x64 tile, 2x2 outputs/thread. grid = (R/64, C/64).
// ---------------------------------------------------------------------------
__global__ __launch_bounds__(1024) void gemm_xwt_kernel(
    const float* __restrict__ X, const float* __restrict__ W,
    const float* __restrict__ bias, float* __restrict__ out, int C) {
  __shared__ float Xs[128][68];   // [k][r], stride 68 -> bank step 4, float4-aligned
  __shared__ float Ws[128][68];
  const int t = threadIdx.x;
  const int r0blk = blockIdx.x * 64;
  const int c0blk = blockIdx.y * 64;

  #pragma unroll
  for (int it = 0; it < 2; ++it) {
    const int f = (t + it * 1024) * 4;   // 0..8188
    const int r = f >> 7;                // 0..63
    const int k = f & 127;
    const float4 xv = *(const float4*)&X[(size_t)(r0blk + r) * 128 + k];
    Xs[k + 0][r] = xv.x; Xs[k + 1][r] = xv.y;
    Xs[k + 2][r] = xv.z; Xs[k + 3][r] = xv.w;
    const float4 wv = *(const float4*)&W[(size_t)(c0blk + r) * 128 + k];
    Ws[k + 0][r] = wv.x; Ws[k + 1][r] = wv.y;
    Ws[k + 2][r] = wv.z; Ws[k + 3][r] = wv.w;
  }
  __syncthreads();

  const int cc = 2 * (t & 31);   // cols vary fastest across lanes -> coalesced C-write
  const int rr = 2 * (t >> 5);
  float a00 = 0.f, a01 = 0.f, a10 = 0.f, a11 = 0.f;

  #pragma unroll 8
  for (int k = 0; k < 128; ++k) {
    const float2 xv = *(const float2*)&Xs[k][rr];
    const float2 wv = *(const float2*)&Ws[k][cc];
    a00 += xv.x * wv.x; a01 += xv.x * wv.y;
    a10 += xv.y * wv.x; a11 += xv.y * wv.y;
  }

  const float b0 = bias[c0blk + cc];
  const float b1 = bias[c0blk + cc + 1];
  float2 o0 = make_float2(a00 + b0, a01 + b1);
  float2 o1 = make_float2(a10 + b0, a11 + b1);
  *(float2*)&out[(size_t)(r0blk + rr + 0) * C + (c0blk + cc)] = o0;
  *(float2*)&out[(size_t)(r0blk + rr + 1) * C + (c0blk + cc)] = o1;
}

// ---------------------------------------------------------------------------
// Sparse masked attention. One block (256 thr) per (b, query-row i).
// Ballot compaction (unordered), compacted score storage, online softmax
// across CHUNK-sized pieces of the active list.
// ---------------------------------------------------------------------------
__global__ __launch_bounds__(256) void attn_kernel(
    const float* __restrict__ Qb, const float* __restrict__ Kb,
    const float* __restrict__ Vb, const float* __restrict__ A,
    float* __restrict__ Y) {
  __shared__ float sQ[128];
  __shared__ float sS[NHEAD][CHUNK + 8];   // stride 520 -> bank step 8
  __shared__ unsigned short sIdx[NNODE];
  __shared__ int sCount;
  __shared__ float sMax[NHEAD];     // chunk max (new running max)
  __shared__ float sScale[NHEAD];   // exp(m_old - m_new)
  __shared__ float sMRun[NHEAD];
  __shared__ float sLRun[NHEAD];
  __shared__ float sOut[128];

  const int b = blockIdx.x >> 10;
  const int i = blockIdx.x & 1023;
  const int t = threadIdx.x;
  const int lane = t & 63;
  const size_t bBase = (size_t)b * NNODE;

  if (t == 0) sCount = 0;
  if (t < NHEAD) { sMRun[t] = -3.0e38f; sLRun[t] = 0.0f; }
  if (t < 128) sQ[t] = Qb[(bBase + i) * 128 + t] * 0.25f;  // 1/sqrt(16)

  // --- compaction: ballot + popcount, one LDS atomic per wave ---
  const float* Arow = A + ((size_t)(b * NNODE + i)) * NNODE;
  const int j0 = t * 4;
  const float4 av = *(const float4*)&Arow[j0];
  const unsigned long long m0 = __ballot(av.x > 0.f);
  const unsigned long long m1 = __ballot(av.y > 0.f);
  const unsigned long long m2 = __ballot(av.z > 0.f);
  const unsigned long long m3 = __ballot(av.w > 0.f);
  const int c0n = __popcll(m0), c1n = __popcll(m1), c2n = __popcll(m2);
  int base = 0;
  if (lane == 0)
    base = atomicAdd(&sCount, c0n + c1n + c2n + __popcll(m3));
  base = __shfl(base, 0);
  const unsigned long long lt = (1ull << lane) - 1ull;
  if (av.x > 0.f) sIdx[base + __popcll(m0 & lt)] = (unsigned short)j0;
  if (av.y > 0.f) sIdx[base + c0n + __popcll(m1 & lt)] = (unsigned short)(j0 + 1);
  if (av.z > 0.f) sIdx[base + c0n + c1n + __popcll(m2 & lt)] = (unsigned short)(j0 + 2);
  if (av.w > 0.f) sIdx[base + c0n + c1n + c2n + __popcll(m3 & lt)] = (unsigned short)(j0 + 3);
  __syncthreads();
  const int cnt = sCount;

  const int hd = t & 127;        // PV feature
  const int half = t >> 7;       // PV slot parity
  const int myh = hd >> 4;       // PV head
  float acc = 0.0f;

  const int hred = t >> 5;       // reduction head (one 32-group per head)
  const int l32 = t & 31;

  for (int c0 = 0; c0 < cnt; c0 += CHUNK) {
    const int cs = min(cnt - c0, CHUNK);
    if (c0) __syncthreads();     // protect sS reuse across chunks

    // --- scores: thread pair (slot, feature-half); half h=0..3 / h=4..7 ---
    {
      const int fh = t & 1;
      const float4* Qr = (const float4*)(sQ + fh * 64);
      for (int s0 = t >> 1; s0 < cs; s0 += 128) {
        const int j = sIdx[c0 + s0];
        const float4* Kr = (const float4*)(Kb + (bBase + j) * 128 + fh * 64);
        float s0v = 0.f, s1v = 0.f, s2v = 0.f, s3v = 0.f;
        #pragma unroll
        for (int q = 0; q < 16; ++q) {
          const float4 kv = Kr[q];
          const float4 qv = Qr[q];
          const float d = qv.x * kv.x + qv.y * kv.y + qv.z * kv.z + qv.w * kv.w;
          if ((q >> 2) == 0) s0v += d;
          else if ((q >> 2) == 1) s1v += d;
          else if ((q >> 2) == 2) s2v += d;
          else s3v += d;
        }
        const int hb = fh * 4;
        sS[hb + 0][s0] = s0v; sS[hb + 1][s0] = s1v;
        sS[hb + 2][s0] = s2v; sS[hb + 3][s0] = s3v;
      }
    }
    __syncthreads();

    // --- chunk max per head (contiguous compacted sweep) ---
    float lmax = -3.0e38f;
    for (int s0 = l32; s0 < cs; s0 += 32) lmax = fmaxf(lmax, sS[hred][s0]);
    #pragma unroll
    for (int off = 16; off >= 1; off >>= 1)
      lmax = fmaxf(lmax, __shfl_xor(lmax, off));
    if (l32 == 0) {
      const float mold = sMRun[hred];
      const float mnew = fmaxf(mold, lmax);
      sMax[hred] = mnew;
      sScale[hred] = __expf(mold - mnew);
      sMRun[hred] = mnew;
    }
    __syncthreads();

    // --- exponentiate in place + chunk sum ---
    {
      const float mx = sMax[hred];
      float lsum = 0.f;
      for (int s0 = l32; s0 < cs; s0 += 32) {
        const float p = __expf(sS[hred][s0] - mx);
        sS[hred][s0] = p;
        lsum += p;
      }
      #pragma unroll
      for (int off = 16; off >= 1; off >>= 1)
        lsum += __shfl_xor(lsum, off);
      if (l32 == 0)
        sLRun[hred] = sLRun[hred] * sScale[hred] + lsum;
    }
    __syncthreads();

    // --- PV accumulate (rescale by chunk scale) ---
    {
      float a2 = 0.f;
      #pragma unroll 4
      for (int s0 = half; s0 < cs; s0 += 2) {
        const int j = sIdx[c0 + s0];
        a2 += sS[myh][s0] * Vb[(bBase + j) * 128 + hd];
      }
      acc = acc * sScale[myh] + a2;
    }
  }

  if (half) sOut[hd] = acc;
  __syncthreads();
  if (t < 128) {
    const float y = (acc + sOut[t]) / sLRun[myh];
    Y[(bBase + i) * 128 + t] = y;
  }
}

// ---------------------------------------------------------------------------
extern "C" void kernel_launch(void* const* d_in, const int* in_sizes, int n_in,
                              void* d_out, int out_size, void* d_ws, size_t ws_size,
                              hipStream_t stream) {
  const float* X  = (const float*)d_in[0];
  const float* A  = (const float*)d_in[1];
  const float* Wq = (const float*)d_in[2];
  const float* bq = (const float*)d_in[3];
  const float* Wk = (const float*)d_in[4];
  const float* bk = (const float*)d_in[5];
  const float* Wv = (const float*)d_in[6];
  const float* bv = (const float*)d_in[7];
  const float* Wo = (const float*)d_in[8];
  const float* bo = (const float*)d_in[9];
  float* out = (float*)d_out;

  const size_t mat = (size_t)BATCH * NNODE * FEAT;  // 4 MB each
  float* Q = (float*)d_ws;
  float* K = Q + mat;
  float* V = K + mat;
  float* Yb = V + mat;

  dim3 gblk(128, 2);
  dim3 tblk(1024);
  hipLaunchKernelGGL(gemm_xwt_kernel, gblk, tblk, 0, stream, X, Wq, bq, Q, FEAT);
  hipLaunchKernelGGL(gemm_xwt_kernel, gblk, tblk, 0, stream, X, Wk, bk, K, FEAT);
  hipLaunchKernelGGL(gemm_xwt_kernel, gblk, tblk, 0, stream, X, Wv, bv, V, FEAT);
  hipLaunchKernelGGL(attn_kernel, dim3(BATCH * NNODE), dim3(256), 0, stream,
                     Q, K, V, A, Yb);
  hipLaunchKernelGGL(gemm_xwt_kernel, gblk, tblk, 0, stream, Yb, Wo, bo, out, FEAT);
}